// Round 9
// baseline (482.330 us; speedup 1.0000x reference)
//
#include <hip/hip_runtime.h>

#define D 128
#define NH 8
#define FOUT 16
#define NEG_SLOPE 0.2f
#define SCAN_BS 1024
#define NREP 8

typedef __attribute__((ext_vector_type(8))) short bf16x8;
typedef __attribute__((ext_vector_type(4))) float f32x4;

__device__ __forceinline__ unsigned enc_f(float f) {
    unsigned u = __float_as_uint(f);
    return (u & 0x80000000u) ? ~u : (u | 0x80000000u);
}
__device__ __forceinline__ float dec_f(unsigned u) {
    u = (u & 0x80000000u) ? (u & 0x7fffffffu) : ~u;
    return __uint_as_float(u);
}
__device__ __forceinline__ unsigned short f2bf(float x) {  // round-to-nearest-even
    unsigned u = __float_as_uint(x);
    return (unsigned short)((u + 0x7fffu + ((u >> 16) & 1u)) >> 16);
}

// ---- prep: pack W_src and wc (a_trg-folded W_trg) into MFMA B-fragment order (bf16)
__global__ __launch_bounds__(1024) void prep_kernel(
    const float* __restrict__ W_src, const float* __restrict__ W_trg,
    const float* __restrict__ a_trg,
    unsigned short* __restrict__ Wfrag, unsigned short* __restrict__ wcfrag) {
    __shared__ float wcs[NH][D];
    int t = threadIdx.x;
    {
        int h = t >> 7, d = t & 127;
        float acc = 0.f;
#pragma unroll
        for (int f = 0; f < FOUT; ++f)
            acc += a_trg[h * FOUT + f] * W_trg[(h * FOUT + f) * D + d];
        wcs[h][d] = acc;
    }
    __syncthreads();
    for (int o = t; o < D * D; o += 1024) {
        int j = o & 7, l = (o >> 3) & 63, c = (o >> 9) & 3, ntl = o >> 11;
        int col = ntl * 16 + (l & 15);
        int k = c * 32 + ((j >> 2) << 4) + (((l >> 4) & 3) << 2) + (j & 3);
        Wfrag[o] = f2bf(W_src[col * D + k]);
    }
    for (int o = t; o < 2048; o += 1024) {
        int j = o & 7, l = (o >> 3) & 63, c = o >> 9;
        int h = l & 15;
        int k = c * 32 + ((j >> 2) << 4) + (((l >> 4) & 3) << 2) + (j & 3);
        wcfrag[o] = (h < NH) ? f2bf(wcs[h][k]) : (unsigned short)0;
    }
}

// ---- MFMA projection: 64 nodes/block, dual LDS tiles, ONE barrier
__global__ __launch_bounds__(256) void proj_kernel(
    const float* __restrict__ src, const float* __restrict__ trg,
    const unsigned short* __restrict__ Wfrag, const unsigned short* __restrict__ wcfrag,
    const float* __restrict__ a_src,
    unsigned short* __restrict__ projb,
    float* __restrict__ s_src, float* __restrict__ s_trg,
    unsigned* __restrict__ gmax_enc, int N) {
    int tid = threadIdx.x;
    int lane = tid & 63;
    int w = tid >> 6;
    int cl = lane & 15, rq = lane >> 4;
    int n0 = blockIdx.x * 64;
    int nodes = min(64, N - n0);
    int nwords = nodes * 32;
    int nb0 = n0 + w * 16;

    __shared__ unsigned short tileS[64][132];
    __shared__ unsigned short tileT[64][132];

    const bf16x8* WF = (const bf16x8*)Wfrag;
    const bf16x8* WCF = (const bf16x8*)wcfrag;

    // stage BOTH operands, then one barrier (16 independent float4 loads in flight)
    {
        const float4* s4 = (const float4*)(src + (size_t)n0 * D);
        const float4* t4 = (const float4*)(trg + (size_t)n0 * D);
        for (int i = tid; i < 2048; i += 256) {
            int r = i >> 5, c = i & 31;
            float4 vs = (i < nwords) ? s4[i] : make_float4(0.f, 0.f, 0.f, 0.f);
            float4 vt = (i < nwords) ? t4[i] : make_float4(0.f, 0.f, 0.f, 0.f);
            ushort4 us, ut;
            us.x = f2bf(vs.x); us.y = f2bf(vs.y); us.z = f2bf(vs.z); us.w = f2bf(vs.w);
            ut.x = f2bf(vt.x); ut.y = f2bf(vt.y); ut.z = f2bf(vt.z); ut.w = f2bf(vt.w);
            *(ushort4*)&tileS[r][c * 4] = us;
            *(ushort4*)&tileT[r][c * 4] = ut;
        }
    }
    __syncthreads();

    // trg score MFMA
    f32x4 acc2 = {0.f, 0.f, 0.f, 0.f};
#pragma unroll
    for (int c = 0; c < 4; ++c) {
        const unsigned short* tp = &tileT[w * 16 + cl][c * 32 + rq * 4];
        union { unsigned long long q[2]; bf16x8 v; } af;
        af.q[0] = *(const unsigned long long*)tp;
        af.q[1] = *(const unsigned long long*)(tp + 16);
        acc2 = __builtin_amdgcn_mfma_f32_16x16x32_bf16(af.v, WCF[c * 64 + lane], acc2, 0, 0, 0);
    }

    // src projection MFMA
    union { unsigned long long q[2]; bf16x8 v; } af0, af1, af2, af3;
    {
        const unsigned short* tp = &tileS[w * 16 + cl][rq * 4];
        af0.q[0] = *(const unsigned long long*)tp;
        af0.q[1] = *(const unsigned long long*)(tp + 16);
        af1.q[0] = *(const unsigned long long*)(tp + 32);
        af1.q[1] = *(const unsigned long long*)(tp + 48);
        af2.q[0] = *(const unsigned long long*)(tp + 64);
        af2.q[1] = *(const unsigned long long*)(tp + 80);
        af3.q[0] = *(const unsigned long long*)(tp + 96);
        af3.q[1] = *(const unsigned long long*)(tp + 112);
    }
    f32x4 acc[8] = {{0.f,0.f,0.f,0.f},{0.f,0.f,0.f,0.f},{0.f,0.f,0.f,0.f},{0.f,0.f,0.f,0.f},
                    {0.f,0.f,0.f,0.f},{0.f,0.f,0.f,0.f},{0.f,0.f,0.f,0.f},{0.f,0.f,0.f,0.f}};
#pragma unroll
    for (int nt = 0; nt < 8; ++nt) {
        acc[nt] = __builtin_amdgcn_mfma_f32_16x16x32_bf16(af0.v, WF[(nt * 4 + 0) * 64 + lane], acc[nt], 0, 0, 0);
        acc[nt] = __builtin_amdgcn_mfma_f32_16x16x32_bf16(af1.v, WF[(nt * 4 + 1) * 64 + lane], acc[nt], 0, 0, 0);
        acc[nt] = __builtin_amdgcn_mfma_f32_16x16x32_bf16(af2.v, WF[(nt * 4 + 2) * 64 + lane], acc[nt], 0, 0, 0);
        acc[nt] = __builtin_amdgcn_mfma_f32_16x16x32_bf16(af3.v, WF[(nt * 4 + 3) * 64 + lane], acc[nt], 0, 0, 0);
    }

    // epilogues
    float lmax = -1e30f, tmax = -1e30f;
#pragma unroll
    for (int i = 0; i < 4; ++i) {
        int node = nb0 + rq * 4 + i;
        if (cl < NH && node < N) {
            float dv = acc2[i];
            s_trg[(size_t)node * NH + cl] = dv;
            tmax = fmaxf(tmax, dv);
        }
    }
#pragma unroll
    for (int nt = 0; nt < 8; ++nt) {
        float av = a_src[nt * FOUT + cl];
#pragma unroll
        for (int i = 0; i < 4; ++i) {
            int node = nb0 + rq * 4 + i;
            float p = acc[nt][i] * av;
            p += __shfl_xor(p, 1); p += __shfl_xor(p, 2);
            p += __shfl_xor(p, 4); p += __shfl_xor(p, 8);
            if (node < N) {
                projb[(size_t)node * D + nt * 16 + cl] = f2bf(acc[nt][i]);
                if (cl == 0) s_src[(size_t)node * NH + nt] = p;
                lmax = fmaxf(lmax, p);
            }
        }
    }
#pragma unroll
    for (int off = 1; off < 64; off <<= 1) {
        lmax = fmaxf(lmax, __shfl_xor(lmax, off));
        tmax = fmaxf(tmax, __shfl_xor(tmax, off));
    }
    if (lane == 0) {
        atomicMax(gmax_enc + 0, enc_f(lmax));
        atomicMax(gmax_enc + 1, enc_f(tmax));
    }
}

// ---- histogram with NREP replicated count arrays (conflict spreading)
__global__ void hist_kernel(const int* __restrict__ ei, int* __restrict__ counts_r,
                            int E, int N) {
    int* c = counts_r + (size_t)(blockIdx.x & (NREP - 1)) * N;
    for (int e = blockIdx.x * blockDim.x + threadIdx.x; e < E;
         e += gridDim.x * blockDim.x)
        atomicAdd(c + ei[E + e], 1);
}

// ---- scan1: sum replicas -> totcnt, exclusive scan -> cursor
__global__ void scan1_kernel(const int* __restrict__ counts_r, int* __restrict__ totcnt,
                             int* __restrict__ cursor, int* __restrict__ bsum, int N) {
    __shared__ int tmp[SCAN_BS];
    int t = threadIdx.x, g = blockIdx.x * SCAN_BS + t;
    int v = 0;
    if (g < N) {
#pragma unroll
        for (int r = 0; r < NREP; ++r) v += counts_r[(size_t)r * N + g];
        totcnt[g] = v;
    }
    tmp[t] = v;
    __syncthreads();
    for (int off = 1; off < SCAN_BS; off <<= 1) {
        int x = (t >= off) ? tmp[t - off] : 0;
        __syncthreads();
        tmp[t] += x;
        __syncthreads();
    }
    if (g < N) cursor[g] = tmp[t] - v;
    if (t == SCAN_BS - 1) bsum[blockIdx.x] = tmp[t];
}
__global__ void scan2_kernel(int* __restrict__ bsum, int nb,
                             const unsigned* __restrict__ ge, float* __restrict__ gmaxf) {
    __shared__ int tmp[128];
    int t = threadIdx.x;
    int v = (t < nb) ? bsum[t] : 0;
    tmp[t] = v;
    __syncthreads();
    for (int off = 1; off < 128; off <<= 1) {
        int x = (t >= off) ? tmp[t - off] : 0;
        __syncthreads();
        tmp[t] += x;
        __syncthreads();
    }
    if (t < nb) bsum[t] = tmp[t] - v;
    if (t == 0) gmaxf[0] = dec_f(ge[0]) + dec_f(ge[1]);  // M >= true max; cancels
}
__global__ void scan3_kernel(int* __restrict__ cursor, const int* __restrict__ bsum, int N) {
    int g = blockIdx.x * SCAN_BS + threadIdx.x;
    if (g < N) cursor[g] += bsum[blockIdx.x];
}

// ---- scatter edges into CSR buckets (2 edges/thread, int2 reads)
__global__ void scatter_kernel(const int* __restrict__ ei, int* __restrict__ cursor,
                               int* __restrict__ perm_src, int E) {
    int e = 2 * (blockIdx.x * blockDim.x + threadIdx.x);
    if (e + 1 < E) {
        int2 s2 = *((const int2*)(ei + e));
        int2 t2 = *((const int2*)(ei + E + e));
        perm_src[atomicAdd(cursor + t2.x, 1)] = s2.x;
        perm_src[atomicAdd(cursor + t2.y, 1)] = s2.y;
    } else if (e < E) {
        int si = ei[e], ti = ei[E + e];
        perm_src[atomicAdd(cursor + ti, 1)] = si;
    }
}

// ---- per-target aggregation: wave per target (4/block), bf16 gather, no barriers
__global__ __launch_bounds__(256) void agg_kernel(
    const int* __restrict__ cursor_end, const int* __restrict__ totcnt,
    const int* __restrict__ perm_src,
    const float* __restrict__ s_src, const float* __restrict__ s_trg,
    const unsigned short* __restrict__ projb, const float* __restrict__ gmaxf,
    float* __restrict__ out, int N) {
    int w = threadIdx.x >> 6;
    int lane = threadIdx.x & 63;     // owns features 2*lane, 2*lane+1
    int n = blockIdx.x * 4 + w;
    if (n >= N) return;
    int h = lane >> 3;
    int cnt = totcnt[n];
    int start = cursor_end[n] - cnt;
    float M = gmaxf[0];
    __shared__ float stg_sh[4][NH];
    __shared__ int sie[4][64];
    __shared__ float wls[4][64][NH + 1];
    if (lane < NH) stg_sh[w][lane] = s_trg[(size_t)n * NH + lane];

    const unsigned* p2 = (const unsigned*)projb;   // bf16x2, row stride 64
    float acc0 = 0.f, acc1 = 0.f, wsum = 0.f;

    for (int base = 0; base < cnt; base += 64) {
        int idx = base + lane;
        if (idx < cnt) {
            int si = perm_src[start + idx];
            sie[w][lane] = si;
            const float* ps = s_src + (size_t)si * NH;
#pragma unroll
            for (int hh = 0; hh < NH; ++hh) {
                float sc = ps[hh] + stg_sh[w][hh];
                sc = sc > 0.f ? sc : NEG_SLOPE * sc;
                wls[w][lane][hh] = __expf(sc - M);
            }
        }
        int m = min(64, cnt - base);
#pragma unroll 4
        for (int j = 0; j < m; ++j) {
            int si = sie[w][j];
            float wgt = wls[w][j][h];
            unsigned pv = p2[(size_t)si * 64 + lane];
            float lo = __uint_as_float(pv << 16);
            float hi = __uint_as_float(pv & 0xffff0000u);
            wsum += wgt;
            acc0 += wgt * lo;
            acc1 += wgt * hi;
        }
    }
    float inv = 1.f / (wsum + 1e-16f);
    *((float2*)(out + (size_t)n * D + 2 * lane)) = make_float2(acc0 * inv, acc1 * inv);
}

extern "C" void kernel_launch(void* const* d_in, const int* in_sizes, int n_in,
                              void* d_out, int out_size, void* d_ws, size_t ws_size,
                              hipStream_t stream) {
    const float* trg   = (const float*)d_in[0];
    const float* src   = (const float*)d_in[1];
    const int*   ei    = (const int*)d_in[2];
    const float* W_trg = (const float*)d_in[3];
    const float* W_src = (const float*)d_in[4];
    const float* a_src = (const float*)d_in[5];
    const float* a_trg = (const float*)d_in[6];
    float* out = (float*)d_out;

    const int N = in_sizes[0] / D;   // 100000
    const int E = in_sizes[2] / 2;   // 1600000

    unsigned short* Wfrag  = (unsigned short*)d_ws;       // 16384 shorts (32 KB)
    unsigned short* wcfrag = Wfrag + D * D;               // 2048 shorts (4 KB)
    unsigned* gmaxe = (unsigned*)(wcfrag + 2048);         // 2 (pad 4)
    float* gmaxf    = (float*)(gmaxe + 4);                // 1 (pad 4)
    float* s_src    = gmaxf + 4;                          // N*8 f
    float* s_trg    = s_src + (size_t)N * NH;             // N*8 f
    int*   counts_r = (int*)(s_trg + (size_t)N * NH);     // NREP*N
    int*   totcnt   = counts_r + (size_t)NREP * N;        // N
    int*   cursor   = totcnt + N;                         // N
    int*   bsum     = cursor + N;                         // 128
    int*   perm_src = bsum + 128;                         // E
    unsigned short* projb = (unsigned short*)(perm_src + E);  // N*128 bf16

    const int NB = (N + SCAN_BS - 1) / SCAN_BS;    // 98
    const int PB = (N + 63) / 64;                  // 1563

    hipMemsetAsync(counts_r, 0, (size_t)NREP * N * sizeof(int), stream);
    hipMemsetAsync(gmaxe, 0, 4 * sizeof(unsigned), stream);

    prep_kernel<<<1, 1024, 0, stream>>>(W_src, W_trg, a_trg, Wfrag, wcfrag);
    proj_kernel<<<PB, 256, 0, stream>>>(src, trg, Wfrag, wcfrag, a_src,
                                        projb, s_src, s_trg, gmaxe, N);
    hist_kernel<<<2048, 256, 0, stream>>>(ei, counts_r, E, N);
    scan1_kernel<<<NB, SCAN_BS, 0, stream>>>(counts_r, totcnt, cursor, bsum, N);
    scan2_kernel<<<1, 128, 0, stream>>>(bsum, NB, gmaxe, gmaxf);
    scan3_kernel<<<NB, SCAN_BS, 0, stream>>>(cursor, bsum, N);
    scatter_kernel<<<(E / 2 + 255) / 256, 256, 0, stream>>>(ei, cursor, perm_src, E);
    agg_kernel<<<(N + 3) / 4, 256, 0, stream>>>(cursor, totcnt, perm_src,
                                                s_src, s_trg, projb, gmaxf, out, N);
}

// Round 10
// 377.483 us; speedup vs baseline: 1.2778x; 1.2778x over previous
//
#include <hip/hip_runtime.h>

#define D 128
#define NH 8
#define FOUT 16
#define NEG_SLOPE 0.2f
#define SCAN_BS 1024
#define NREP 8

typedef __attribute__((ext_vector_type(8))) short bf16x8;
typedef __attribute__((ext_vector_type(4))) float f32x4;

__device__ __forceinline__ unsigned short f2bf(float x) {  // round-to-nearest-even
    unsigned u = __float_as_uint(x);
    return (unsigned short)((u + 0x7fffu + ((u >> 16) & 1u)) >> 16);
}

// ---- prep: pack W_src and wc (a_trg-folded W_trg) into MFMA B-fragment order (bf16)
__global__ __launch_bounds__(1024) void prep_kernel(
    const float* __restrict__ W_src, const float* __restrict__ W_trg,
    const float* __restrict__ a_trg,
    unsigned short* __restrict__ Wfrag, unsigned short* __restrict__ wcfrag) {
    __shared__ float wcs[NH][D];
    int t = threadIdx.x;
    {
        int h = t >> 7, d = t & 127;
        float acc = 0.f;
#pragma unroll
        for (int f = 0; f < FOUT; ++f)
            acc += a_trg[h * FOUT + f] * W_trg[(h * FOUT + f) * D + d];
        wcs[h][d] = acc;
    }
    __syncthreads();
    for (int o = t; o < D * D; o += 1024) {
        int j = o & 7, l = (o >> 3) & 63, c = (o >> 9) & 3, ntl = o >> 11;
        int col = ntl * 16 + (l & 15);
        int k = c * 32 + ((j >> 2) << 4) + (((l >> 4) & 3) << 2) + (j & 3);
        Wfrag[o] = f2bf(W_src[col * D + k]);
    }
    for (int o = t; o < 2048; o += 1024) {
        int j = o & 7, l = (o >> 3) & 63, c = o >> 9;
        int h = l & 15;
        int k = c * 32 + ((j >> 2) << 4) + (((l >> 4) & 3) << 2) + (j & 3);
        wcfrag[o] = (h < NH) ? f2bf(wcs[h][k]) : (unsigned short)0;
    }
}

// ---- MFMA projection: 64 nodes/block, dual LDS tiles, one barrier,
//      deep-pipelined branch-free staging, NO global atomics
__global__ __launch_bounds__(256) void proj_kernel(
    const float* __restrict__ src, const float* __restrict__ trg,
    const unsigned short* __restrict__ Wfrag, const unsigned short* __restrict__ wcfrag,
    const float* __restrict__ a_src,
    unsigned short* __restrict__ projb,
    float* __restrict__ s_src, float* __restrict__ s_trg,
    float* __restrict__ wmaxS, float* __restrict__ wmaxT, int N) {
    int tid = threadIdx.x;
    int lane = tid & 63;
    int w = tid >> 6;
    int cl = lane & 15, rq = lane >> 4;
    int n0 = blockIdx.x * 64;
    int nodes = min(64, N - n0);
    int nb0 = n0 + w * 16;

    __shared__ unsigned short tileS[64][132];
    __shared__ unsigned short tileT[64][132];

    const bf16x8* WF = (const bf16x8*)Wfrag;
    const bf16x8* WCF = (const bf16x8*)wcfrag;

    // stage BOTH operands: 16 independent loads all issued before any use
    {
        const float4* s4 = (const float4*)src;
        const float4* t4 = (const float4*)trg;
        float4 vs[8], vt[8];
#pragma unroll
        for (int k = 0; k < 8; ++k) {
            int i = tid + k * 256;
            int r = i >> 5, c = i & 31;
            int rr = (r < nodes) ? r : (nodes - 1);   // clamp: garbage rows masked later
            size_t gi = (size_t)(n0 + rr) * 32 + c;
            vs[k] = s4[gi];
            vt[k] = t4[gi];
        }
#pragma unroll
        for (int k = 0; k < 8; ++k) {
            int i = tid + k * 256;
            int r = i >> 5, c = i & 31;
            ushort4 us, ut;
            us.x = f2bf(vs[k].x); us.y = f2bf(vs[k].y);
            us.z = f2bf(vs[k].z); us.w = f2bf(vs[k].w);
            ut.x = f2bf(vt[k].x); ut.y = f2bf(vt[k].y);
            ut.z = f2bf(vt[k].z); ut.w = f2bf(vt[k].w);
            *(ushort4*)&tileS[r][c * 4] = us;
            *(ushort4*)&tileT[r][c * 4] = ut;
        }
    }
    __syncthreads();

    // trg score MFMA
    f32x4 acc2 = {0.f, 0.f, 0.f, 0.f};
#pragma unroll
    for (int c = 0; c < 4; ++c) {
        const unsigned short* tp = &tileT[w * 16 + cl][c * 32 + rq * 4];
        union { unsigned long long q[2]; bf16x8 v; } af;
        af.q[0] = *(const unsigned long long*)tp;
        af.q[1] = *(const unsigned long long*)(tp + 16);
        acc2 = __builtin_amdgcn_mfma_f32_16x16x32_bf16(af.v, WCF[c * 64 + lane], acc2, 0, 0, 0);
    }

    // src projection MFMA
    union { unsigned long long q[2]; bf16x8 v; } af0, af1, af2, af3;
    {
        const unsigned short* tp = &tileS[w * 16 + cl][rq * 4];
        af0.q[0] = *(const unsigned long long*)tp;
        af0.q[1] = *(const unsigned long long*)(tp + 16);
        af1.q[0] = *(const unsigned long long*)(tp + 32);
        af1.q[1] = *(const unsigned long long*)(tp + 48);
        af2.q[0] = *(const unsigned long long*)(tp + 64);
        af2.q[1] = *(const unsigned long long*)(tp + 80);
        af3.q[0] = *(const unsigned long long*)(tp + 96);
        af3.q[1] = *(const unsigned long long*)(tp + 112);
    }
    f32x4 acc[8] = {{0.f,0.f,0.f,0.f},{0.f,0.f,0.f,0.f},{0.f,0.f,0.f,0.f},{0.f,0.f,0.f,0.f},
                    {0.f,0.f,0.f,0.f},{0.f,0.f,0.f,0.f},{0.f,0.f,0.f,0.f},{0.f,0.f,0.f,0.f}};
#pragma unroll
    for (int nt = 0; nt < 8; ++nt) {
        acc[nt] = __builtin_amdgcn_mfma_f32_16x16x32_bf16(af0.v, WF[(nt * 4 + 0) * 64 + lane], acc[nt], 0, 0, 0);
        acc[nt] = __builtin_amdgcn_mfma_f32_16x16x32_bf16(af1.v, WF[(nt * 4 + 1) * 64 + lane], acc[nt], 0, 0, 0);
        acc[nt] = __builtin_amdgcn_mfma_f32_16x16x32_bf16(af2.v, WF[(nt * 4 + 2) * 64 + lane], acc[nt], 0, 0, 0);
        acc[nt] = __builtin_amdgcn_mfma_f32_16x16x32_bf16(af3.v, WF[(nt * 4 + 3) * 64 + lane], acc[nt], 0, 0, 0);
    }

    // epilogues (no atomics; per-wave maxes to global arrays)
    float lmax = -1e30f, tmax = -1e30f;
#pragma unroll
    for (int i = 0; i < 4; ++i) {
        int node = nb0 + rq * 4 + i;
        if (cl < NH && node < N) {
            float dv = acc2[i];
            s_trg[(size_t)node * NH + cl] = dv;
            tmax = fmaxf(tmax, dv);
        }
    }
#pragma unroll
    for (int nt = 0; nt < 8; ++nt) {
        float av = a_src[nt * FOUT + cl];
#pragma unroll
        for (int i = 0; i < 4; ++i) {
            int node = nb0 + rq * 4 + i;
            float p = acc[nt][i] * av;
            p += __shfl_xor(p, 1); p += __shfl_xor(p, 2);
            p += __shfl_xor(p, 4); p += __shfl_xor(p, 8);
            if (node < N) {
                projb[(size_t)node * D + nt * 16 + cl] = f2bf(acc[nt][i]);
                if (cl == 0) s_src[(size_t)node * NH + nt] = p;
                lmax = fmaxf(lmax, p);
            }
        }
    }
#pragma unroll
    for (int off = 1; off < 64; off <<= 1) {
        lmax = fmaxf(lmax, __shfl_xor(lmax, off));
        tmax = fmaxf(tmax, __shfl_xor(tmax, off));
    }
    if (lane == 0) {
        wmaxS[blockIdx.x * 4 + w] = lmax;
        wmaxT[blockIdx.x * 4 + w] = tmax;
    }
}

// ---- histogram with NREP replicated count arrays
__global__ void hist_kernel(const int* __restrict__ ei, int* __restrict__ counts_r,
                            int E, int N) {
    int* c = counts_r + (size_t)(blockIdx.x & (NREP - 1)) * N;
    for (int e = blockIdx.x * blockDim.x + threadIdx.x; e < E;
         e += gridDim.x * blockDim.x)
        atomicAdd(c + ei[E + e], 1);
}

// ---- scan1: sum replicas -> totcnt, exclusive scan -> cursor
__global__ void scan1_kernel(const int* __restrict__ counts_r, int* __restrict__ totcnt,
                             int* __restrict__ cursor, int* __restrict__ bsum, int N) {
    __shared__ int tmp[SCAN_BS];
    int t = threadIdx.x, g = blockIdx.x * SCAN_BS + t;
    int v = 0;
    if (g < N) {
#pragma unroll
        for (int r = 0; r < NREP; ++r) v += counts_r[(size_t)r * N + g];
        totcnt[g] = v;
    }
    tmp[t] = v;
    __syncthreads();
    for (int off = 1; off < SCAN_BS; off <<= 1) {
        int x = (t >= off) ? tmp[t - off] : 0;
        __syncthreads();
        tmp[t] += x;
        __syncthreads();
    }
    if (g < N) cursor[g] = tmp[t] - v;
    if (t == SCAN_BS - 1) bsum[blockIdx.x] = tmp[t];
}

// ---- scan2: block offsets + deterministic global max from per-wave maxes
__global__ void scan2_kernel(int* __restrict__ bsum, int nb,
                             const float* __restrict__ wmaxS,
                             const float* __restrict__ wmaxT,
                             int nw, float* __restrict__ gmaxf) {
    __shared__ int tmp[128];
    __shared__ float r1[128], r2[128];
    int t = threadIdx.x;
    int v = (t < nb) ? bsum[t] : 0;
    tmp[t] = v;
    __syncthreads();
    for (int off = 1; off < 128; off <<= 1) {
        int x = (t >= off) ? tmp[t - off] : 0;
        __syncthreads();
        tmp[t] += x;
        __syncthreads();
    }
    if (t < nb) bsum[t] = tmp[t] - v;
    float m1 = -1e30f, m2 = -1e30f;
    for (int i = t; i < nw; i += 128) {
        m1 = fmaxf(m1, wmaxS[i]);
        m2 = fmaxf(m2, wmaxT[i]);
    }
    r1[t] = m1; r2[t] = m2;
    __syncthreads();
    for (int s = 64; s; s >>= 1) {
        if (t < s) {
            r1[t] = fmaxf(r1[t], r1[t + s]);
            r2[t] = fmaxf(r2[t], r2[t + s]);
        }
        __syncthreads();
    }
    if (t == 0) gmaxf[0] = r1[0] + r2[0];  // M >= true max; cancels in softmax
}
__global__ void scan3_kernel(int* __restrict__ cursor, const int* __restrict__ bsum, int N) {
    int g = blockIdx.x * SCAN_BS + threadIdx.x;
    if (g < N) cursor[g] += bsum[blockIdx.x];
}

// ---- scatter edges into CSR buckets (2 edges/thread, int2 reads)
__global__ void scatter_kernel(const int* __restrict__ ei, int* __restrict__ cursor,
                               int* __restrict__ perm_src, int E) {
    int e = 2 * (blockIdx.x * blockDim.x + threadIdx.x);
    if (e + 1 < E) {
        int2 s2 = *((const int2*)(ei + e));
        int2 t2 = *((const int2*)(ei + E + e));
        perm_src[atomicAdd(cursor + t2.x, 1)] = s2.x;
        perm_src[atomicAdd(cursor + t2.y, 1)] = s2.y;
    } else if (e < E) {
        int si = ei[e], ti = ei[E + e];
        perm_src[atomicAdd(cursor + ti, 1)] = si;
    }
}

// ---- per-target aggregation: wave per target (4/block), bf16 gather, no barriers
__global__ __launch_bounds__(256) void agg_kernel(
    const int* __restrict__ cursor_end, const int* __restrict__ totcnt,
    const int* __restrict__ perm_src,
    const float* __restrict__ s_src, const float* __restrict__ s_trg,
    const unsigned short* __restrict__ projb, const float* __restrict__ gmaxf,
    float* __restrict__ out, int N) {
    int w = threadIdx.x >> 6;
    int lane = threadIdx.x & 63;     // owns features 2*lane, 2*lane+1
    int n = blockIdx.x * 4 + w;
    if (n >= N) return;
    int h = lane >> 3;
    int cnt = totcnt[n];
    int start = cursor_end[n] - cnt;
    float M = gmaxf[0];
    __shared__ float stg_sh[4][NH];
    __shared__ int sie[4][64];
    __shared__ float wls[4][64][NH + 1];
    if (lane < NH) stg_sh[w][lane] = s_trg[(size_t)n * NH + lane];

    const unsigned* p2 = (const unsigned*)projb;   // bf16x2, row stride 64
    float acc0 = 0.f, acc1 = 0.f, wsum = 0.f;

    for (int base = 0; base < cnt; base += 64) {
        int idx = base + lane;
        if (idx < cnt) {
            int si = perm_src[start + idx];
            sie[w][lane] = si;
            const float* ps = s_src + (size_t)si * NH;
#pragma unroll
            for (int hh = 0; hh < NH; ++hh) {
                float sc = ps[hh] + stg_sh[w][hh];
                sc = sc > 0.f ? sc : NEG_SLOPE * sc;
                wls[w][lane][hh] = __expf(sc - M);
            }
        }
        int m = min(64, cnt - base);
#pragma unroll 4
        for (int j = 0; j < m; ++j) {
            int si = sie[w][j];
            float wgt = wls[w][j][h];
            unsigned pv = p2[(size_t)si * 64 + lane];
            float lo = __uint_as_float(pv << 16);
            float hi = __uint_as_float(pv & 0xffff0000u);
            wsum += wgt;
            acc0 += wgt * lo;
            acc1 += wgt * hi;
        }
    }
    float inv = 1.f / (wsum + 1e-16f);
    *((float2*)(out + (size_t)n * D + 2 * lane)) = make_float2(acc0 * inv, acc1 * inv);
}

extern "C" void kernel_launch(void* const* d_in, const int* in_sizes, int n_in,
                              void* d_out, int out_size, void* d_ws, size_t ws_size,
                              hipStream_t stream) {
    const float* trg   = (const float*)d_in[0];
    const float* src   = (const float*)d_in[1];
    const int*   ei    = (const int*)d_in[2];
    const float* W_trg = (const float*)d_in[3];
    const float* W_src = (const float*)d_in[4];
    const float* a_src = (const float*)d_in[5];
    const float* a_trg = (const float*)d_in[6];
    float* out = (float*)d_out;

    const int N = in_sizes[0] / D;   // 100000
    const int E = in_sizes[2] / 2;   // 1600000

    const int PB = (N + 63) / 64;    // 1563
    const int NW = PB * 4;           // per-wave max slots

    unsigned short* Wfrag  = (unsigned short*)d_ws;       // 16384 shorts (32 KB)
    unsigned short* wcfrag = Wfrag + D * D;               // 2048 shorts (4 KB)
    float* gmaxf    = (float*)(wcfrag + 2048);            // 1 (pad 4)
    float* wmaxS    = gmaxf + 4;                          // NW
    float* wmaxT    = wmaxS + NW;                         // NW
    float* s_src    = wmaxT + NW;                         // N*8 f
    float* s_trg    = s_src + (size_t)N * NH;             // N*8 f
    int*   counts_r = (int*)(s_trg + (size_t)N * NH);     // NREP*N
    int*   totcnt   = counts_r + (size_t)NREP * N;        // N
    int*   cursor   = totcnt + N;                         // N
    int*   bsum     = cursor + N;                         // 128
    int*   perm_src = bsum + 128;                         // E
    unsigned short* projb = (unsigned short*)(perm_src + E);  // N*128 bf16

    const int NB = (N + SCAN_BS - 1) / SCAN_BS;    // 98

    hipMemsetAsync(counts_r, 0, (size_t)NREP * N * sizeof(int), stream);

    prep_kernel<<<1, 1024, 0, stream>>>(W_src, W_trg, a_trg, Wfrag, wcfrag);
    proj_kernel<<<PB, 256, 0, stream>>>(src, trg, Wfrag, wcfrag, a_src,
                                        projb, s_src, s_trg, wmaxS, wmaxT, N);
    hist_kernel<<<2048, 256, 0, stream>>>(ei, counts_r, E, N);
    scan1_kernel<<<NB, SCAN_BS, 0, stream>>>(counts_r, totcnt, cursor, bsum, N);
    scan2_kernel<<<1, 128, 0, stream>>>(bsum, NB, wmaxS, wmaxT, NW, gmaxf);
    scan3_kernel<<<NB, SCAN_BS, 0, stream>>>(cursor, bsum, N);
    scatter_kernel<<<(E / 2 + 255) / 256, 256, 0, stream>>>(ei, cursor, perm_src, E);
    agg_kernel<<<(N + 3) / 4, 256, 0, stream>>>(cursor, totcnt, perm_src,
                                                s_src, s_trg, projb, gmaxf, out, N);
}